// Round 1
// baseline (238335.547 us; speedup 1.0000x reference)
//
#include <hip/hip_runtime.h>
#include <cmath>

// ---------------------------------------------------------------------------
// FDFD Ez solve via adjoint trick:
//   out[b,o] = sigmoid(-(c0*|s_b^T z_o| - E0[o])*alpha),  A^T z_o = p_o
// Two independent BiCGSTAB solves (one workgroup each), matrix-free 5-point
// stencil with SC-PML stretch coefficients computed in-kernel.
// ---------------------------------------------------------------------------

namespace {
constexpr int NXg  = 128;
constexpr int NYg  = 52;
constexpr int Ng   = NXg * NYg;       // 6656
constexpr int NPMLg = 10;
constexpr int NT   = 768;             // threads per block (12 waves)
constexpr int CPT  = 9;               // cells per thread: 768*9 = 6912 >= 6656
constexpr int NW   = NT / 64;         // 12 waves
constexpr int MAXIT = 6000;

constexpr double D_PI    = 3.14159265358979323846;
constexpr double D_DL    = 2.5e-8;
constexpr double D_EPS0  = 8.85418782e-12;
constexpr double D_MU0   = 4e-7 * D_PI;
constexpr double D_OMEGA = 2.0 * D_PI * 2e14;
}

__device__ __forceinline__ float2 cmulf(float2 a, float2 b) {
    return make_float2(a.x * b.x - a.y * b.y, a.x * b.y + a.y * b.x);
}
__device__ __forceinline__ float2 caddf(float2 a, float2 b) {
    return make_float2(a.x + b.x, a.y + b.y);
}
__device__ __forceinline__ float2 csubf(float2 a, float2 b) {
    return make_float2(a.x - b.x, a.y - b.y);
}
__device__ __forceinline__ float2 cdivf(float2 a, float2 b) {
    float d = b.x * b.x + b.y * b.y;
    return make_float2((a.x * b.x + a.y * b.y) / d, (a.y * b.x - a.x * b.y) / d);
}

// SC-PML stretch factor s = 1 - i*sigma/(omega*eps0) at fractional position pos
__device__ inline double2 sfac(int n, double pos) {
    double dlo = fmax((double)NPMLg - pos, 0.0);
    double dhi = fmax(pos - (double)(n - 1 - NPMLg), 0.0);
    double dpml = NPMLg * D_DL;
    double d = fmax(dlo, dhi) * D_DL;
    double eta0 = sqrt(D_MU0 / D_EPS0);
    double smax = -4.0 * log(1e-8) / (2.0 * eta0 * dpml);
    double t = d / dpml;
    double sigma = smax * t * t * t;
    return double2{1.0, -sigma / (D_OMEGA * D_EPS0)};
}

// float2( 1 / (a*b) ) computed in double
__device__ inline float2 recip_prod(double2 a, double2 b) {
    double pr = a.x * b.x - a.y * b.y;
    double pi = a.x * b.y + a.y * b.x;
    double den = pr * pr + pi * pi;
    return make_float2((float)(pr / den), (float)(-pi / den));
}

// 4-wide block reduction (sum) over NT threads; result broadcast to all.
__device__ __forceinline__ float4 blockReduce4(float4 v, float4* red, int tid) {
    #pragma unroll
    for (int off = 32; off > 0; off >>= 1) {
        v.x += __shfl_down(v.x, off);
        v.y += __shfl_down(v.y, off);
        v.z += __shfl_down(v.z, off);
        v.w += __shfl_down(v.w, off);
    }
    __syncthreads();                       // protect red[] from previous use
    if ((tid & 63) == 0) red[tid >> 6] = v;
    __syncthreads();
    float4 a = red[0];
    #pragma unroll
    for (int w = 1; w < NW; ++w) {
        a.x += red[w].x; a.y += red[w].y; a.z += red[w].z; a.w += red[w].w;
    }
    return a;
}

// y = A^T * src  (5-point stencil, periodic wrap, transposed coefficients)
__device__ __forceinline__ void matvecT(const float2 (&src)[CPT], float2 (&dst)[CPT],
                                        const float2 (&dg)[CPT], float2* s_z,
                                        const float2* s_cxp, const float2* s_cxm,
                                        const float2* s_cyp, const float2* s_cym,
                                        int tid) {
    __syncthreads();   // previous consumers of s_z are done
    #pragma unroll
    for (int k = 0; k < CPT; ++k) {
        int c = tid + NT * k;
        if (c < Ng) s_z[c] = src[k];
    }
    __syncthreads();
    #pragma unroll
    for (int k = 0; k < CPT; ++k) {
        int c = tid + NT * k;
        if (c >= Ng) continue;
        int ix = c / NYg;
        int iy = c - ix * NYg;
        int xp = (ix + 1 < NXg) ? ix + 1 : 0;
        int xm = (ix > 0) ? ix - 1 : NXg - 1;
        int yp = (iy + 1 < NYg) ? iy + 1 : 0;
        int ym = (iy > 0) ? iy - 1 : NYg - 1;
        int nxp = xp * NYg + iy;
        int nxm = xm * NYg + iy;
        int nyp = ix * NYg + yp;
        int nym = ix * NYg + ym;
        float2 acc = cmulf(dg[k], s_z[c]);
        acc = caddf(acc, cmulf(s_cxm[xp], s_z[nxp]));   // A^T: +x neighbor <- cxm(ix+1)
        acc = caddf(acc, cmulf(s_cxp[xm], s_z[nxm]));   // A^T: -x neighbor <- cxp(ix-1)
        acc = caddf(acc, cmulf(s_cym[yp], s_z[nyp]));   // A^T: +y neighbor <- cym(iy+1)
        acc = caddf(acc, cmulf(s_cyp[ym], s_z[nym]));   // A^T: -y neighbor <- cyp(iy-1)
        dst[k] = acc;
    }
}

__global__ void __launch_bounds__(NT, 3)
fdfd_kernel(const float* __restrict__ masks, const float* __restrict__ rho_in,
            const float* __restrict__ E0s, const float* __restrict__ alpha_in,
            const float* __restrict__ ics, const float* __restrict__ probes,
            const float* __restrict__ bg_rho, const float* __restrict__ opt_region,
            float* __restrict__ out) {
    const int tid = threadIdx.x;
    const int o = blockIdx.x;   // probe index 0 / 1

    __shared__ float2 s_z[Ng];
    __shared__ float2 s_r0[Ng];
    __shared__ float2 s_cxp[NXg], s_cxm[NXg];
    __shared__ float2 s_cyp[NYg], s_cym[NYg];
    __shared__ float4 s_red[NW];

    // ---- 1-D PML stretch coefficient arrays ------------------------------
    if (tid < NXg) {
        int ix = tid;
        double2 sf  = sfac(NXg, (double)ix + 0.5);
        double2 sb0 = sfac(NXg, (double)ix);
        double2 sb1 = sfac(NXg, (double)((ix + 1) % NXg));
        s_cxp[ix] = recip_prod(sf, sb1);
        s_cxm[ix] = recip_prod(sf, sb0);
    } else if (tid < NXg + NYg) {
        int iy = tid - NXg;
        double2 sf  = sfac(NYg, (double)iy + 0.5);
        double2 sb0 = sfac(NYg, (double)iy);
        double2 sb1 = sfac(NYg, (double)((iy + 1) % NYg));
        s_cyp[iy] = recip_prod(sf, sb1);
        s_cym[iy] = recip_prod(sf, sb0);
    }
    __syncthreads();

    // ---- per-cell state in registers -------------------------------------
    const float k2 = (float)((D_OMEGA * D_DL) * (D_OMEGA * D_DL) * D_MU0 * D_EPS0);
    float2 xv[CPT], rv[CPT], pv[CPT], vv[CPT], tv[CPT], dg[CPT];
    float4 part = make_float4(0.f, 0.f, 0.f, 0.f);
    #pragma unroll
    for (int k = 0; k < CPT; ++k) {
        int c = tid + NT * k;
        xv[k] = pv[k] = vv[k] = tv[k] = make_float2(0.f, 0.f);
        rv[k] = make_float2(0.f, 0.f);
        dg[k] = make_float2(0.f, 0.f);
        if (c < Ng) {
            int ix = c / NYg;
            int iy = c - ix * NYg;
            float rt = opt_region[c] * rho_in[c] + (1.f - opt_region[c]) * bg_rho[c];
            rt = fminf(fmaxf(rt, 0.f), 1.f);
            float epsr = 1.f + 11.f * rt;
            float2 d = caddf(caddf(s_cxp[ix], s_cxm[ix]), caddf(s_cyp[iy], s_cym[iy]));
            d = make_float2(-d.x + k2 * epsr, -d.y);
            dg[k] = d;
            float bb = probes[o * Ng + c];
            rv[k] = make_float2(bb, 0.f);
            s_r0[c] = rv[k];
            part.x += bb * bb;
        }
    }
    float bnorm2 = blockReduce4(part, s_red, tid).x;
    float tol2 = bnorm2 * 1e-12f;   // rel residual 1e-6

    // ---- BiCGSTAB for A^T z = p ------------------------------------------
    float2 rho_o  = make_float2(1.f, 0.f);
    float2 alpha_c = make_float2(1.f, 0.f);
    float2 omega_c = make_float2(1.f, 0.f);

    for (int it = 0; it < MAXIT; ++it) {
        // rho = <r0, r>
        part = make_float4(0.f, 0.f, 0.f, 0.f);
        #pragma unroll
        for (int k = 0; k < CPT; ++k) {
            int c = tid + NT * k;
            if (c < Ng) {
                float2 r0c = s_r0[c];
                part.x += r0c.x * rv[k].x + r0c.y * rv[k].y;
                part.y += r0c.x * rv[k].y - r0c.y * rv[k].x;
            }
        }
        float4 rr = blockReduce4(part, s_red, tid);
        float2 rho_c = make_float2(rr.x, rr.y);

        float rod = rho_o.x * rho_o.x + rho_o.y * rho_o.y;
        float omd = omega_c.x * omega_c.x + omega_c.y * omega_c.y;
        if (rod == 0.f || omd == 0.f) break;                 // breakdown
        float2 beta = cmulf(cdivf(rho_c, rho_o), cdivf(alpha_c, omega_c));

        // p = r + beta*(p - omega*v)
        #pragma unroll
        for (int k = 0; k < CPT; ++k)
            pv[k] = caddf(rv[k], cmulf(beta, csubf(pv[k], cmulf(omega_c, vv[k]))));

        // v = A^T p
        matvecT(pv, vv, dg, s_z, s_cxp, s_cxm, s_cyp, s_cym, tid);

        // gamma = <r0, v>
        part = make_float4(0.f, 0.f, 0.f, 0.f);
        #pragma unroll
        for (int k = 0; k < CPT; ++k) {
            int c = tid + NT * k;
            if (c < Ng) {
                float2 r0c = s_r0[c];
                part.x += r0c.x * vv[k].x + r0c.y * vv[k].y;
                part.y += r0c.x * vv[k].y - r0c.y * vv[k].x;
            }
        }
        rr = blockReduce4(part, s_red, tid);
        float2 gamma = make_float2(rr.x, rr.y);
        if (gamma.x * gamma.x + gamma.y * gamma.y == 0.f) break;
        alpha_c = cdivf(rho_c, gamma);

        // s = r - alpha*v   (stored in rv)
        #pragma unroll
        for (int k = 0; k < CPT; ++k)
            rv[k] = csubf(rv[k], cmulf(alpha_c, vv[k]));

        // t = A^T s
        matvecT(rv, tv, dg, s_z, s_cxp, s_cxm, s_cyp, s_cym, tid);

        // <t,s>, <t,t>, <s,s>
        part = make_float4(0.f, 0.f, 0.f, 0.f);
        #pragma unroll
        for (int k = 0; k < CPT; ++k) {
            int c = tid + NT * k;
            if (c < Ng) {
                part.x += tv[k].x * rv[k].x + tv[k].y * rv[k].y;
                part.y += tv[k].x * rv[k].y - tv[k].y * rv[k].x;
                part.z += tv[k].x * tv[k].x + tv[k].y * tv[k].y;
                part.w += rv[k].x * rv[k].x + rv[k].y * rv[k].y;
            }
        }
        rr = blockReduce4(part, s_red, tid);
        float2 ts = make_float2(rr.x, rr.y);
        float tt = rr.z, ss = rr.w;
        omega_c = (tt > 0.f) ? make_float2(ts.x / tt, ts.y / tt) : make_float2(0.f, 0.f);

        // x += alpha*p + omega*s ;  r = s - omega*t
        #pragma unroll
        for (int k = 0; k < CPT; ++k) {
            xv[k] = caddf(xv[k], caddf(cmulf(alpha_c, pv[k]), cmulf(omega_c, rv[k])));
            rv[k] = csubf(rv[k], cmulf(omega_c, tv[k]));
        }
        float rn2 = ss - 2.f * (omega_c.x * ts.x + omega_c.y * ts.y)
                  + (omega_c.x * omega_c.x + omega_c.y * omega_c.y) * tt;
        if (!(rn2 > tol2)) break;    // converged (or NaN) -> stop
        rho_o = rho_c;
    }

    // ---- outputs: q_i = ics_i^T z ; out[b,o] = sigmoid(-(c0*|m@q| - E0)*al)
    part = make_float4(0.f, 0.f, 0.f, 0.f);
    #pragma unroll
    for (int k = 0; k < CPT; ++k) {
        int c = tid + NT * k;
        if (c < Ng) {
            float i0 = ics[c];
            float i1 = ics[Ng + c];
            part.x += i0 * xv[k].x;
            part.y += i0 * xv[k].y;
            part.z += i1 * xv[k].x;
            part.w += i1 * xv[k].y;
        }
    }
    float4 q = blockReduce4(part, s_red, tid);

    if (tid == 0) {
        const float c0 = (float)(D_OMEGA * D_MU0 * D_DL * D_DL);
        float E0 = E0s[o];
        float al = alpha_in[0];
        #pragma unroll
        for (int b = 0; b < 8; ++b) {
            float m0 = masks[2 * b], m1 = masks[2 * b + 1];
            float re = m0 * q.x + m1 * q.z;
            float im = m0 * q.y + m1 * q.w;
            float ov = c0 * sqrtf(re * re + im * im);
            out[2 * b + o] = 1.f / (1.f + expf((ov - E0) * al));
        }
    }
}

extern "C" void kernel_launch(void* const* d_in, const int* in_sizes, int n_in,
                              void* d_out, int out_size, void* d_ws, size_t ws_size,
                              hipStream_t stream) {
    (void)in_sizes; (void)n_in; (void)d_ws; (void)ws_size; (void)out_size;
    fdfd_kernel<<<dim3(2), dim3(NT), 0, stream>>>(
        (const float*)d_in[0],   // masks   (8,2)
        (const float*)d_in[1],   // rho     (128,52)
        (const float*)d_in[2],   // E0s     (2,)
        (const float*)d_in[3],   // alpha   (1,)
        (const float*)d_in[4],   // ics     (2,128,52)
        (const float*)d_in[5],   // probes  (2,128,52)
        (const float*)d_in[6],   // bg_rho  (128,52)
        (const float*)d_in[7],   // opt_region (128,52)
        (float*)d_out);          // (8,2) float32
}

// Round 2
// 27862.332 us; speedup vs baseline: 8.5540x; 8.5540x over previous
//
#include <hip/hip_runtime.h>
#include <cmath>

// ---------------------------------------------------------------------------
// FDFD Ez solve, adjoint + symmetrized:
//   out[b,o] = sigmoid(-(c0*|s_b^T z_o| - E0[o])*alpha),  A^T z_o = p_o
// With D = diag(sqrt(sxf)*sqrt(syf)):  B = D A D^-1 is complex-symmetric, so
//   A^T z = p  <=>  B y = D^-1 p,  z = D y.
// Solve B y = rhs with COCG (complex-symmetric CG, unconjugated dots):
//   1 matvec + 2 reductions per iteration; state x,r,diag in regs, p in LDS.
// Two independent solves (one workgroup per probe).
// ---------------------------------------------------------------------------

namespace {
constexpr int NXg   = 128;
constexpr int NYg   = 52;
constexpr int Ng    = NXg * NYg;      // 6656
constexpr int NPMLg = 10;
constexpr int NT    = 768;            // 12 waves
constexpr int CPT   = 9;              // 768*9 = 6912 >= 6656
constexpr int NW    = NT / 64;
constexpr int MAXIT = 4000;

constexpr double D_PI    = 3.14159265358979323846;
constexpr double D_DL    = 2.5e-8;
constexpr double D_EPS0  = 8.85418782e-12;
constexpr double D_MU0   = 4e-7 * D_PI;
constexpr double D_OMEGA = 2.0 * D_PI * 2e14;
}

// ---- double-precision complex helpers (init only) -------------------------
struct dcx { double x, y; };
__device__ __forceinline__ dcx dmul(dcx a, dcx b) {
    return {a.x * b.x - a.y * b.y, a.x * b.y + a.y * b.x};
}
__device__ __forceinline__ dcx dadd(dcx a, dcx b) { return {a.x + b.x, a.y + b.y}; }
__device__ __forceinline__ dcx drec(dcx a) {
    double d = a.x * a.x + a.y * a.y;
    return {a.x / d, -a.y / d};
}
__device__ __forceinline__ dcx dsqr(dcx a) {   // principal sqrt (a in 4th quadrant here)
    double r = sqrt(a.x * a.x + a.y * a.y);
    double re = sqrt(0.5 * (r + a.x));
    double im = sqrt(0.5 * fmax(r - a.x, 0.0));
    if (a.y < 0.0) im = -im;
    return {re, im};
}
__device__ __forceinline__ float2 tof2(dcx a) { return make_float2((float)a.x, (float)a.y); }

// ---- float complex helpers ------------------------------------------------
__device__ __forceinline__ float2 cmulf(float2 a, float2 b) {
    return make_float2(a.x * b.x - a.y * b.y, a.x * b.y + a.y * b.x);
}
__device__ __forceinline__ float2 caddf(float2 a, float2 b) {
    return make_float2(a.x + b.x, a.y + b.y);
}
__device__ __forceinline__ float2 csubf(float2 a, float2 b) {
    return make_float2(a.x - b.x, a.y - b.y);
}
__device__ __forceinline__ float2 cdivf(float2 a, float2 b) {
    float d = b.x * b.x + b.y * b.y;
    return make_float2((a.x * b.x + a.y * b.y) / d, (a.y * b.x - a.x * b.y) / d);
}

// SC-PML stretch factor s = 1 - i*sigma/(omega*eps0)
__device__ inline dcx sfac(int n, double pos) {
    double dlo = fmax((double)NPMLg - pos, 0.0);
    double dhi = fmax(pos - (double)(n - 1 - NPMLg), 0.0);
    double dpml = NPMLg * D_DL;
    double d = fmax(dlo, dhi) * D_DL;
    double eta0 = sqrt(D_MU0 / D_EPS0);
    double smax = -4.0 * log(1e-8) / (2.0 * eta0 * dpml);
    double t = d / dpml;
    double sigma = smax * t * t * t;
    return dcx{1.0, -sigma / (D_OMEGA * D_EPS0)};
}

// 4-wide block sum; result broadcast to all threads.
__device__ __forceinline__ float4 blockReduce4(float4 v, float4* red, int tid) {
    #pragma unroll
    for (int off = 32; off > 0; off >>= 1) {
        v.x += __shfl_down(v.x, off);
        v.y += __shfl_down(v.y, off);
        v.z += __shfl_down(v.z, off);
        v.w += __shfl_down(v.w, off);
    }
    __syncthreads();                       // protect red[] reuse
    if ((tid & 63) == 0) red[tid >> 6] = v;
    __syncthreads();
    float4 a = red[0];
    #pragma unroll
    for (int w = 1; w < NW; ++w) {
        a.x += red[w].x; a.y += red[w].y; a.z += red[w].z; a.w += red[w].w;
    }
    return a;
}

__global__ void __launch_bounds__(NT, 1)
fdfd_cocg(const float* __restrict__ masks, const float* __restrict__ rho_in,
          const float* __restrict__ E0s, const float* __restrict__ alpha_in,
          const float* __restrict__ ics, const float* __restrict__ probes,
          const float* __restrict__ bg_rho, const float* __restrict__ opt_region,
          float* __restrict__ out) {
    const int tid = threadIdx.x;
    const int o = blockIdx.x;      // probe index

    __shared__ float2 s_p[Ng];                       // search direction (stencil src)
    __shared__ float2 s_gx[NXg], s_cx[NXg], s_rx[NXg];
    __shared__ float2 s_gy[NYg], s_cy[NYg], s_ry[NYg];
    __shared__ float4 s_red[NW];

    // ---- 1-D coefficient arrays (double precision init) ------------------
    if (tid < NXg) {
        int ix = tid;
        int ixp = (ix + 1 < NXg) ? ix + 1 : 0;
        dcx f0 = sfac(NXg, (double)ix + 0.5);
        dcx f1 = sfac(NXg, (double)ixp + 0.5);
        dcx b0 = sfac(NXg, (double)ix);
        dcx b1 = sfac(NXg, (double)ixp);
        dcx cxp = drec(dmul(f0, b1));
        dcx cxm = drec(dmul(f0, b0));
        s_cx[ix] = tof2(dadd(cxp, cxm));                         // cxp+cxm (for diag)
        s_gx[ix] = tof2(drec(dmul(b1, dmul(dsqr(f0), dsqr(f1))))); // sym edge coeff ix<->ix+1
        s_rx[ix] = tof2(dsqr(f0));                               // sqrt(sxf)
    } else if (tid < NXg + NYg) {
        int iy = tid - NXg;
        int iyp = (iy + 1 < NYg) ? iy + 1 : 0;
        dcx f0 = sfac(NYg, (double)iy + 0.5);
        dcx f1 = sfac(NYg, (double)iyp + 0.5);
        dcx b0 = sfac(NYg, (double)iy);
        dcx b1 = sfac(NYg, (double)iyp);
        dcx cyp = drec(dmul(f0, b1));
        dcx cym = drec(dmul(f0, b0));
        s_cy[iy] = tof2(dadd(cyp, cym));
        s_gy[iy] = tof2(drec(dmul(b1, dmul(dsqr(f0), dsqr(f1)))));
        s_ry[iy] = tof2(dsqr(f0));
    }
    __syncthreads();

    // ---- per-cell init: diag, rhs = probe / d, p = r, rho0 = (r,r) -------
    const float k2 = (float)((D_OMEGA * D_DL) * (D_OMEGA * D_DL) * D_MU0 * D_EPS0);
    float2 xv[CPT], rv[CPT], dg[CPT];
    float4 part = make_float4(0.f, 0.f, 0.f, 0.f);
    #pragma unroll
    for (int k = 0; k < CPT; ++k) {
        int c = tid + NT * k;
        xv[k] = make_float2(0.f, 0.f);
        rv[k] = make_float2(0.f, 0.f);
        dg[k] = make_float2(1.f, 0.f);
        if (c < Ng) {
            int ix = c / NYg;
            int iy = c - ix * NYg;
            float rt = opt_region[c] * rho_in[c] + (1.f - opt_region[c]) * bg_rho[c];
            rt = fminf(fmaxf(rt, 0.f), 1.f);
            float epsr = 1.f + 11.f * rt;
            float2 d2 = caddf(s_cx[ix], s_cy[iy]);
            dg[k] = make_float2(-d2.x + k2 * epsr, -d2.y);
            float2 dd = cmulf(s_rx[ix], s_ry[iy]);      // D_ii
            float pb = probes[o * Ng + c];
            rv[k] = cdivf(make_float2(pb, 0.f), dd);    // rhs = D^-1 p
            s_p[c] = rv[k];
            part.x += rv[k].x * rv[k].x - rv[k].y * rv[k].y;   // unconj (r,r)
            part.y += 2.f * rv[k].x * rv[k].y;
            part.z += rv[k].x * rv[k].x + rv[k].y * rv[k].y;   // ||r||^2
        }
    }
    float4 ri = blockReduce4(part, s_red, tid);
    float2 rho = make_float2(ri.x, ri.y);
    const float tol2 = ri.z * 1e-10f;    // rel residual 1e-5

    // ---- COCG main loop ---------------------------------------------------
    for (int it = 0; it < MAXIT; ++it) {
        __syncthreads();                 // s_p writes visible to all
        float2 qv[CPT];
        part = make_float4(0.f, 0.f, 0.f, 0.f);
        #pragma unroll
        for (int k = 0; k < CPT; ++k) {
            int c = tid + NT * k;
            qv[k] = make_float2(0.f, 0.f);
            if (c < Ng) {
                int ix = c / NYg;
                int iy = c - ix * NYg;
                int xp = (ix + 1 < NXg) ? ix + 1 : 0;
                int xm = (ix > 0) ? ix - 1 : NXg - 1;
                int yp = (iy + 1 < NYg) ? iy + 1 : 0;
                int ym = (iy > 0) ? iy - 1 : NYg - 1;
                float2 pc = s_p[c];
                float2 acc = cmulf(dg[k], pc);
                acc = caddf(acc, cmulf(s_gx[ix], s_p[xp * NYg + iy]));
                acc = caddf(acc, cmulf(s_gx[xm], s_p[xm * NYg + iy]));
                acc = caddf(acc, cmulf(s_gy[iy], s_p[ix * NYg + yp]));
                acc = caddf(acc, cmulf(s_gy[ym], s_p[ix * NYg + ym]));
                qv[k] = acc;
                part.x += pc.x * acc.x - pc.y * acc.y;     // unconj (p,q)
                part.y += pc.x * acc.y + pc.y * acc.x;
            }
        }
        float4 rr = blockReduce4(part, s_red, tid);
        float2 pq = make_float2(rr.x, rr.y);
        if (pq.x * pq.x + pq.y * pq.y == 0.f) break;       // breakdown
        float2 al = cdivf(rho, pq);

        part = make_float4(0.f, 0.f, 0.f, 0.f);
        #pragma unroll
        for (int k = 0; k < CPT; ++k) {
            int c = tid + NT * k;
            if (c < Ng) {
                float2 pc = s_p[c];
                xv[k] = caddf(xv[k], cmulf(al, pc));
                rv[k] = csubf(rv[k], cmulf(al, qv[k]));
                part.x += rv[k].x * rv[k].x - rv[k].y * rv[k].y;
                part.y += 2.f * rv[k].x * rv[k].y;
                part.z += rv[k].x * rv[k].x + rv[k].y * rv[k].y;
            }
        }
        rr = blockReduce4(part, s_red, tid);               // after this, s_p reads done
        float rn2 = rr.z;
        float2 rho_n = make_float2(rr.x, rr.y);
        if (!(rn2 > tol2)) break;                          // converged / NaN
        float rd = rho.x * rho.x + rho.y * rho.y;
        if (rd == 0.f) break;                              // breakdown
        float2 be = cdivf(rho_n, rho);
        rho = rho_n;
        #pragma unroll
        for (int k = 0; k < CPT; ++k) {
            int c = tid + NT * k;
            if (c < Ng) s_p[c] = caddf(rv[k], cmulf(be, s_p[c]));   // own cell only
        }
    }

    // ---- output: z = D y ; q_i = ics_i^T z ; sigmoid --------------------
    part = make_float4(0.f, 0.f, 0.f, 0.f);
    #pragma unroll
    for (int k = 0; k < CPT; ++k) {
        int c = tid + NT * k;
        if (c < Ng) {
            int ix = c / NYg;
            int iy = c - ix * NYg;
            float2 dd = cmulf(s_rx[ix], s_ry[iy]);
            float2 z = cmulf(dd, xv[k]);
            float i0 = ics[c];
            float i1 = ics[Ng + c];
            part.x += i0 * z.x;
            part.y += i0 * z.y;
            part.z += i1 * z.x;
            part.w += i1 * z.y;
        }
    }
    float4 q = blockReduce4(part, s_red, tid);

    if (tid == 0) {
        const float c0 = (float)(D_OMEGA * D_MU0 * D_DL * D_DL);
        float E0 = E0s[o];
        float al = alpha_in[0];
        #pragma unroll
        for (int b = 0; b < 8; ++b) {
            float m0 = masks[2 * b], m1 = masks[2 * b + 1];
            float re = m0 * q.x + m1 * q.z;
            float im = m0 * q.y + m1 * q.w;
            float ov = c0 * sqrtf(re * re + im * im);
            out[2 * b + o] = 1.f / (1.f + expf((ov - E0) * al));
        }
    }
}

extern "C" void kernel_launch(void* const* d_in, const int* in_sizes, int n_in,
                              void* d_out, int out_size, void* d_ws, size_t ws_size,
                              hipStream_t stream) {
    (void)in_sizes; (void)n_in; (void)d_ws; (void)ws_size; (void)out_size;
    fdfd_cocg<<<dim3(2), dim3(NT), 0, stream>>>(
        (const float*)d_in[0],   // masks      (8,2)
        (const float*)d_in[1],   // rho        (128,52)
        (const float*)d_in[2],   // E0s        (2,)
        (const float*)d_in[3],   // alpha      (1,)
        (const float*)d_in[4],   // ics        (2,128,52)
        (const float*)d_in[5],   // probes     (2,128,52)
        (const float*)d_in[6],   // bg_rho     (128,52)
        (const float*)d_in[7],   // opt_region (128,52)
        (float*)d_out);          // (8,2) float32
}

// Round 3
// 26637.271 us; speedup vs baseline: 8.9474x; 1.0460x over previous
//
#include <hip/hip_runtime.h>
#include <cmath>

// ---------------------------------------------------------------------------
// FDFD Ez solve, adjoint + symmetrized, pipelined COCG:
//   out[b,o] = sigmoid(-(c0*|s_b^T z_o| - E0[o])*alpha),  A^T z_o = p_o
// D = diag(sqrt(sxf)*sqrt(syf)):  B = D A D^-1 complex-symmetric,
//   A^T z = p  <=>  B y = D^-1 p,  z = D y.
// COCG with ONE fused 13-float reduction per iteration:
//   (p,q)u, (r,r)u [exact rho for alpha], ||r||^2 [conv test],
//   (r,q)u,(q,q)u [recurrence -> beta], w_i = (D ics_i, p)u [x never stored:
//   ics-projection q_i accumulated as q_i += alpha*w_i in wave 0].
// 3 barriers/iter. One workgroup per probe; LDS >80KB forces 1 block/CU.
// ---------------------------------------------------------------------------

namespace {
constexpr int NXg   = 128;
constexpr int NYg   = 52;
constexpr int Ng    = NXg * NYg;      // 6656
constexpr int NPMLg = 10;
constexpr int NT    = 512;            // 8 waves
constexpr int CPT   = 13;             // 512*13 = 6656 exactly
constexpr int NW    = NT / 64;        // 8
constexpr int NZMAX = 1280;           // also pads LDS >80KB -> 1 block/CU
constexpr int MAXIT = 4000;

constexpr double D_PI    = 3.14159265358979323846;
constexpr double D_DL    = 2.5e-8;
constexpr double D_EPS0  = 8.85418782e-12;
constexpr double D_MU0   = 4e-7 * D_PI;
constexpr double D_OMEGA = 2.0 * D_PI * 2e14;
}

// ---- double complex helpers (init only) -----------------------------------
struct dcx { double x, y; };
__device__ __forceinline__ dcx dmul(dcx a, dcx b) {
    return {a.x * b.x - a.y * b.y, a.x * b.y + a.y * b.x};
}
__device__ __forceinline__ dcx dadd(dcx a, dcx b) { return {a.x + b.x, a.y + b.y}; }
__device__ __forceinline__ dcx drec(dcx a) {
    double d = a.x * a.x + a.y * a.y;
    return {a.x / d, -a.y / d};
}
__device__ __forceinline__ dcx dsqr(dcx a) {   // principal sqrt
    double r = sqrt(a.x * a.x + a.y * a.y);
    double re = sqrt(0.5 * (r + a.x));
    double im = sqrt(0.5 * fmax(r - a.x, 0.0));
    if (a.y < 0.0) im = -im;
    return {re, im};
}
__device__ __forceinline__ float2 tof2(dcx a) { return make_float2((float)a.x, (float)a.y); }

// ---- float complex helpers ------------------------------------------------
__device__ __forceinline__ float2 cmulf(float2 a, float2 b) {
    return make_float2(a.x * b.x - a.y * b.y, a.x * b.y + a.y * b.x);
}
__device__ __forceinline__ float2 caddf(float2 a, float2 b) {
    return make_float2(a.x + b.x, a.y + b.y);
}
__device__ __forceinline__ float2 csubf(float2 a, float2 b) {
    return make_float2(a.x - b.x, a.y - b.y);
}
__device__ __forceinline__ float2 cdivf(float2 a, float2 b) {
    float d = b.x * b.x + b.y * b.y;
    return make_float2((a.x * b.x + a.y * b.y) / d, (a.y * b.x - a.x * b.y) / d);
}

// SC-PML stretch factor s = 1 - i*sigma/(omega*eps0)
__device__ inline dcx sfac(int n, double pos) {
    double dlo = fmax((double)NPMLg - pos, 0.0);
    double dhi = fmax(pos - (double)(n - 1 - NPMLg), 0.0);
    double dpml = NPMLg * D_DL;
    double d = fmax(dlo, dhi) * D_DL;
    double eta0 = sqrt(D_MU0 / D_EPS0);
    double smax = -4.0 * log(1e-8) / (2.0 * eta0 * dpml);
    double t = d / dpml;
    double sigma = smax * t * t * t;
    return dcx{1.0, -sigma / (D_OMEGA * D_EPS0)};
}

__global__ void __launch_bounds__(NT, 2)
fdfd_pcocg(const float* __restrict__ masks, const float* __restrict__ rho_in,
           const float* __restrict__ E0s, const float* __restrict__ alpha_in,
           const float* __restrict__ ics, const float* __restrict__ probes,
           const float* __restrict__ bg_rho, const float* __restrict__ opt_region,
           float* __restrict__ out) {
    const int tid  = threadIdx.x;
    const int lane = tid & 63;
    const int wid  = tid >> 6;
    const int o    = blockIdx.x;   // probe index

    __shared__ float2 s_p[Ng];                         // 53248 B
    __shared__ float  s_part[NW][16];                  // 512 B
    __shared__ float4 s_scal4;                         // alpha, beta
    __shared__ int    s_flag, s_cnt;
    __shared__ float2 s_gx[NXg], s_cxs[NXg], s_rx[NXg];
    __shared__ float2 s_gy[NYg], s_cys[NYg], s_ry[NYg];
    __shared__ int    s_nzi[NZMAX];                    // nonzero-source cells
    __shared__ float4 s_nzw[NZMAX];                    // (ics0*D, ics1*D)

    if (tid == 0) s_cnt = 0;

    // ---- 1-D coefficient arrays (double precision init) ------------------
    if (tid < NXg) {
        int ix = tid;
        int ixp = (ix + 1 < NXg) ? ix + 1 : 0;
        dcx f0 = sfac(NXg, (double)ix + 0.5);
        dcx f1 = sfac(NXg, (double)ixp + 0.5);
        dcx b0 = sfac(NXg, (double)ix);
        dcx b1 = sfac(NXg, (double)ixp);
        dcx cxp = drec(dmul(f0, b1));
        dcx cxm = drec(dmul(f0, b0));
        s_cxs[ix] = tof2(dadd(cxp, cxm));
        s_gx[ix]  = tof2(drec(dmul(b1, dmul(dsqr(f0), dsqr(f1)))));
        s_rx[ix]  = tof2(dsqr(f0));
    } else if (tid < NXg + NYg) {
        int iy = tid - NXg;
        int iyp = (iy + 1 < NYg) ? iy + 1 : 0;
        dcx f0 = sfac(NYg, (double)iy + 0.5);
        dcx f1 = sfac(NYg, (double)iyp + 0.5);
        dcx b0 = sfac(NYg, (double)iy);
        dcx b1 = sfac(NYg, (double)iyp);
        dcx cyp = drec(dmul(f0, b1));
        dcx cym = drec(dmul(f0, b0));
        s_cys[iy] = tof2(dadd(cyp, cym));
        s_gy[iy]  = tof2(drec(dmul(b1, dmul(dsqr(f0), dsqr(f1)))));
        s_ry[iy]  = tof2(dsqr(f0));
    }
    __syncthreads();

    // ---- per-cell init ----------------------------------------------------
    const float k2 = (float)((D_OMEGA * D_DL) * (D_OMEGA * D_DL) * D_MU0 * D_EPS0);
    float2 pown[CPT], rv[CPT], dg[CPT];
    float rn2p = 0.f;
    #pragma unroll
    for (int k = 0; k < CPT; ++k) {
        int c = tid + NT * k;
        int ix = c / NYg;
        int iy = c - ix * NYg;
        float rt = opt_region[c] * rho_in[c] + (1.f - opt_region[c]) * bg_rho[c];
        rt = fminf(fmaxf(rt, 0.f), 1.f);
        float epsr = 1.f + 11.f * rt;
        float2 d2 = caddf(s_cxs[ix], s_cys[iy]);
        dg[k] = make_float2(-d2.x + k2 * epsr, -d2.y);
        float2 dd = cmulf(s_rx[ix], s_ry[iy]);         // D_ii
        float pb = probes[o * Ng + c];
        float2 r0 = cdivf(make_float2(pb, 0.f), dd);   // rhs = D^-1 p
        rv[k] = r0;
        pown[k] = r0;
        s_p[c] = r0;
        rn2p += r0.x * r0.x + r0.y * r0.y;
        // nonzero-source list (ics sparse): w_i weight = ics_i * D_ii
        float i0 = ics[c];
        float i1 = ics[Ng + c];
        if (i0 != 0.f || i1 != 0.f) {
            int idx = atomicAdd(&s_cnt, 1);
            if (idx < NZMAX) {
                s_nzi[idx] = c;
                float2 w0 = make_float2(i0 * dd.x, i0 * dd.y);
                float2 w1 = make_float2(i1 * dd.x, i1 * dd.y);
                s_nzw[idx] = make_float4(w0.x, w0.y, w1.x, w1.y);
            }
        }
    }
    // init reduce: ||rhs||^2 -> tol2 (wave0 only)
    #pragma unroll
    for (int s = 32; s > 0; s >>= 1) rn2p += __shfl_xor(rn2p, s);
    if (lane == 0) s_part[wid][0] = rn2p;
    __syncthreads();
    float tol2 = 0.f;
    if (wid == 0) {
        float s = 0.f;
        #pragma unroll
        for (int w = 0; w < NW; ++w) s += s_part[w][0];
        tol2 = s * 1e-9f;      // rel residual ~3e-5
    }
    const int cnt = min(s_cnt, NZMAX);

    float2 qacc0 = make_float2(0.f, 0.f);
    float2 qacc1 = make_float2(0.f, 0.f);

    // ---- pipelined COCG main loop ----------------------------------------
    for (int it = 0; it < MAXIT; ++it) {
        __syncthreads();                               // bar1: p visible
        float2 qv[CPT];
        float prt[13];
        #pragma unroll
        for (int j = 0; j < 13; ++j) prt[j] = 0.f;

        #pragma unroll
        for (int k = 0; k < CPT; ++k) {
            int c = tid + NT * k;
            int ix = c / NYg;
            int iy = c - ix * NYg;
            int ixm = (ix > 0) ? ix - 1 : NXg - 1;
            int iym = (iy > 0) ? iy - 1 : NYg - 1;
            int cxp = (ix + 1 < NXg) ? c + NYg : c - (NXg - 1) * NYg;
            int cxm = (ix > 0) ? c - NYg : c + (NXg - 1) * NYg;
            int cyp = (iy + 1 < NYg) ? c + 1 : c - (NYg - 1);
            int cym = (iy > 0) ? c - 1 : c + (NYg - 1);
            float2 q = cmulf(dg[k], pown[k]);
            q = caddf(q, cmulf(s_gx[ix],  s_p[cxp]));
            q = caddf(q, cmulf(s_gx[ixm], s_p[cxm]));
            q = caddf(q, cmulf(s_gy[iy],  s_p[cyp]));
            q = caddf(q, cmulf(s_gy[iym], s_p[cym]));
            qv[k] = q;
            float2 p = pown[k], r = rv[k];
            prt[0] += p.x * q.x - p.y * q.y;     // (p,q)u
            prt[1] += p.x * q.y + p.y * q.x;
            prt[2] += r.x * r.x - r.y * r.y;     // (r,r)u  (exact rho_t)
            prt[3] += 2.f * r.x * r.y;
            prt[4] += r.x * r.x + r.y * r.y;     // ||r||^2 (conv test)
            prt[5] += r.x * q.x - r.y * q.y;     // (r,q)u
            prt[6] += r.x * q.y + r.y * q.x;
            prt[7] += q.x * q.x - q.y * q.y;     // (q,q)u
            prt[8] += 2.f * q.x * q.y;
        }
        if (tid < cnt) {                          // sparse source projections
            float2 pc = s_p[s_nzi[tid]];
            float4 w4 = s_nzw[tid];
            prt[9]  += w4.x * pc.x - w4.y * pc.y;   // (D ics0, p)u
            prt[10] += w4.x * pc.y + w4.y * pc.x;
            prt[11] += w4.z * pc.x - w4.w * pc.y;   // (D ics1, p)u
            prt[12] += w4.z * pc.y + w4.w * pc.x;
        }
        #pragma unroll
        for (int s = 32; s > 0; s >>= 1) {
            #pragma unroll
            for (int j = 0; j < 13; ++j) prt[j] += __shfl_xor(prt[j], s);
        }
        if (lane == 0) {
            #pragma unroll
            for (int j = 0; j < 13; ++j) s_part[wid][j] = prt[j];
        }
        __syncthreads();                               // bar2
        if (wid == 0) {
            float red[13];
            #pragma unroll
            for (int j = 0; j < 13; ++j) {
                float s = 0.f;
                #pragma unroll
                for (int w = 0; w < NW; ++w) s += s_part[w][j];
                red[j] = s;
            }
            float2 pq  = make_float2(red[0], red[1]);
            float2 rho = make_float2(red[2], red[3]);
            float  rn2 = red[4];
            float2 rqu = make_float2(red[5], red[6]);
            float2 qqu = make_float2(red[7], red[8]);
            float pqm  = pq.x * pq.x + pq.y * pq.y;
            int cont = (rn2 > tol2) && (pqm > 0.f);
            if (cont) {
                float2 al = cdivf(rho, pq);
                // rho_{t+1} = rho_t - 2 al (r,q)u + al^2 (q,q)u
                float2 rho_n = csubf(rho, cmulf(make_float2(2.f * al.x, 2.f * al.y), rqu));
                rho_n = caddf(rho_n, cmulf(cmulf(al, al), qqu));
                float2 be = cdivf(rho_n, rho);
                qacc0 = caddf(qacc0, cmulf(al, make_float2(red[9],  red[10])));
                qacc1 = caddf(qacc1, cmulf(al, make_float2(red[11], red[12])));
                if (lane == 0) {
                    s_scal4 = make_float4(al.x, al.y, be.x, be.y);
                    s_flag = 1;
                }
            } else if (lane == 0) {
                s_flag = 0;
            }
        }
        __syncthreads();                               // bar3
        if (s_flag == 0) break;
        float4 ab = s_scal4;
        float2 al = make_float2(ab.x, ab.y);
        float2 be = make_float2(ab.z, ab.w);
        #pragma unroll
        for (int k = 0; k < CPT; ++k) {
            rv[k] = csubf(rv[k], cmulf(al, qv[k]));
            float2 pn = caddf(rv[k], cmulf(be, pown[k]));
            pown[k] = pn;
            s_p[tid + NT * k] = pn;
        }
    }

    // ---- epilogue (wave0 holds qacc = ics_i^T (D y) = ics_i^T z) ---------
    if (tid == 0) {
        const float c0 = (float)(D_OMEGA * D_MU0 * D_DL * D_DL);
        float E0 = E0s[o];
        float al = alpha_in[0];
        #pragma unroll
        for (int b = 0; b < 8; ++b) {
            float m0 = masks[2 * b], m1 = masks[2 * b + 1];
            float re = m0 * qacc0.x + m1 * qacc1.x;
            float im = m0 * qacc0.y + m1 * qacc1.y;
            float ov = c0 * sqrtf(re * re + im * im);
            out[2 * b + o] = 1.f / (1.f + expf((ov - E0) * al));
        }
    }
}

extern "C" void kernel_launch(void* const* d_in, const int* in_sizes, int n_in,
                              void* d_out, int out_size, void* d_ws, size_t ws_size,
                              hipStream_t stream) {
    (void)in_sizes; (void)n_in; (void)d_ws; (void)ws_size; (void)out_size;
    fdfd_pcocg<<<dim3(2), dim3(NT), 0, stream>>>(
        (const float*)d_in[0],   // masks      (8,2)
        (const float*)d_in[1],   // rho        (128,52)
        (const float*)d_in[2],   // E0s        (2,)
        (const float*)d_in[3],   // alpha      (1,)
        (const float*)d_in[4],   // ics        (2,128,52)
        (const float*)d_in[5],   // probes     (2,128,52)
        (const float*)d_in[6],   // bg_rho     (128,52)
        (const float*)d_in[7],   // opt_region (128,52)
        (float*)d_out);          // (8,2) float32
}